// Round 14
// baseline (190.661 us; speedup 1.0000x reference)
//
#include <hip/hip_runtime.h>

// CausalSelfAttention on MI355X (gfx950), bf16 MFMA pipeline.
// B=2 T=2048 C=1024 NH=16 HD=64.  M=B*T=4096.
//
// R25: uniform <=8-tile split-K attention.  R13 counters: attn 41.5 us with
// ~2.5 us/tile under 4-way contention and max chain 16 -> 16x2.5 ~= 40 ~=
// measured: makespan sits ON the contended-chain bound (pipes 57% busy;
// aggregate floor ~24-28 us).  So: nch(qt) = ceil((qt+1)/8) in {1,2,3,4};
// 80 blocks/bh -> grid (32,80) = 2560 blocks, heavy chunks first.  Chain
// bound 8x2.5 ~= 20 us.  Costs: partial writes +16 MB, combine nch<=4 over
// qt 8..31 (~7 us).  Slot layout 4 chunks/qt (64 MB o_part in 256 MB ws).
// Diagonal mask (kt==qt) and epilogues untouched; only block table, slot
// indices, combine nch loop change — deterministic, refcheck-catchable.
// GEMMs/prep byte-frozen (R4-exact cores; QKV 48 us structure ceiling).

typedef __attribute__((ext_vector_type(8))) short short8;   // 8 x bf16 (4 VGPR)
typedef __attribute__((ext_vector_type(4))) short short4v;  // 4 x bf16 (2 VGPR, align 8)
typedef __attribute__((ext_vector_type(4))) float f32x4;    // MFMA 16x16 acc
typedef __attribute__((ext_vector_type(2))) unsigned int u32x2;

#define MFMA16(a, b, c) __builtin_amdgcn_mfma_f32_16x16x32_bf16((a), (b), (c), 0, 0, 0)
#define MFMA16K16(a, b, c) __builtin_amdgcn_mfma_f32_16x16x16bf16_1k((a), (b), (c), 0, 0, 0)

__device__ __forceinline__ unsigned short f2bf(float f) {
  unsigned u = __builtin_bit_cast(unsigned, f);
  u += 0x7fffu + ((u >> 16) & 1u);   // RNE
  return (unsigned short)(u >> 16);
}

__device__ __forceinline__ unsigned short f2bf_fast(float f) {
  // round-half-up: cheaper (2 VALU); |err| <= 2^-9 rel, fine for P/y
  return (unsigned short)((__builtin_bit_cast(unsigned, f) + 0x8000u) >> 16);
}

#if __has_builtin(__builtin_amdgcn_cvt_pk_bf16_f32)
typedef __attribute__((ext_vector_type(2))) __bf16 bf16x2;
__device__ __forceinline__ short4v pack_bf16x4(float a, float b, float c, float d) {
  bf16x2 lo = __builtin_amdgcn_cvt_pk_bf16_f32(a, b);
  bf16x2 hi = __builtin_amdgcn_cvt_pk_bf16_f32(c, d);
  u32x2 t;
  t[0] = __builtin_bit_cast(unsigned, lo);
  t[1] = __builtin_bit_cast(unsigned, hi);
  return __builtin_bit_cast(short4v, t);
}
#else
__device__ __forceinline__ short4v pack_bf16x4(float a, float b, float c, float d) {
  short4v r;
  r[0] = (short)f2bf_fast(a); r[1] = (short)f2bf_fast(b);
  r[2] = (short)f2bf_fast(c); r[3] = (short)f2bf_fast(d);
  return r;
}
#endif

__device__ __forceinline__ short4v pack_rne4(float a, float b, float c, float d) {
  short4v r;
  r[0] = (short)f2bf(a); r[1] = (short)f2bf(b);
  r[2] = (short)f2bf(c); r[3] = (short)f2bf(d);
  return r;
}

__device__ __forceinline__ void gl2lds16(const void* g, void* l) {
  // async global->LDS, 16B/lane; LDS dest = wave-uniform base + lane*16
  __builtin_amdgcn_global_load_lds(
      (__attribute__((address_space(1))) void*)g,
      (__attribute__((address_space(3))) void*)l,
      16, 0, 0);
}

// ---------------- merged prep: x->bf16 + both weight transposes ----------------
// blocks [0,4096): conv x (4096x1024 fp32 -> bf16)
// blocks [4096,4864): Wqkv (1024x3072) -> Wqkv^T bf16 (3072x1024), 48x16 tiles
// blocks [4864,5120): Wproj (1024x1024) -> Wproj^T bf16, 16x16 tiles
// Branch is block-uniform, so the __syncthreads in the transpose path is safe.
__global__ __launch_bounds__(256)
void prep(const float* __restrict__ x, unsigned short* __restrict__ xb,
          const float* __restrict__ Wqkv, unsigned short* __restrict__ wqkvT,
          const float* __restrict__ Wproj, unsigned short* __restrict__ wprojT) {
  __shared__ float tile[64][65];
  const int bx = blockIdx.x, tid = threadIdx.x;
  if (bx < 4096) {
    const int i = (bx * 256 + tid) * 4;
    float4 f = *(const float4*)(x + i);
    unsigned long long r = (unsigned long long)f2bf(f.x)
        | ((unsigned long long)f2bf(f.y) << 16)
        | ((unsigned long long)f2bf(f.z) << 32)
        | ((unsigned long long)f2bf(f.w) << 48);
    *(unsigned long long*)(xb + i) = r;
    return;
  }
  const float* W;
  unsigned short* WT;
  int n0, k0, N;
  if (bx < 4864) {
    const int idx = bx - 4096;            // 48 x 16 tiles, N=3072
    W = Wqkv; WT = wqkvT; N = 3072;
    n0 = (idx % 48) * 64; k0 = (idx / 48) * 64;
  } else {
    const int idx = bx - 4864;            // 16 x 16 tiles, N=1024
    W = Wproj; WT = wprojT; N = 1024;
    n0 = (idx % 16) * 64; k0 = (idx / 16) * 64;
  }
  const int K = 1024;
  const int c = tid & 63, rbase = tid >> 6;  // 4 rows per pass, 16 passes
#pragma unroll
  for (int i = 0; i < 16; ++i) {
    int r = i * 4 + rbase;
    tile[r][c] = W[(size_t)(k0 + r) * N + n0 + c];
  }
  __syncthreads();
#pragma unroll
  for (int i = 0; i < 16; ++i) {
    int r = i * 4 + rbase;
    WT[(size_t)(n0 + r) * K + k0 + c] = f2bf(tile[c][r]);
  }
}

// ---------------- GEMM core: staging + MFMA loop ----------------
// R1 structure: single-buffered 32 KB LDS -> ~3 blocks/CU; stage -> sync ->
// compute -> sync; cross-block TLP hides the drain.
template <int MT>
__device__ __forceinline__ void gemm_core(
    const unsigned short* __restrict__ gA,
    const unsigned short* __restrict__ gB,
    unsigned short* As, unsigned short* Bs,
    int Kdim, int wave, int quad, int lr, int wm, int wn,
    f32x4 (&acc)[MT / 32][4]) {
  constexpr int IF = MT / 32;
  constexpr int RA = MT / 32;
  const size_t rstep = (size_t)32 * Kdim;
  for (int k0 = 0; k0 < Kdim; k0 += 64) {
#pragma unroll
    for (int rd = 0; rd < RA; ++rd)
      gl2lds16(gA + k0 + rd * rstep, As + rd * 2048 + wave * 512);
#pragma unroll
    for (int rd = 0; rd < 4; ++rd)
      gl2lds16(gB + k0 + rd * rstep, Bs + rd * 2048 + wave * 512);
    __syncthreads();
#pragma unroll
    for (int s = 0; s < 2; ++s) {
      const int sw = ((s * 4 + quad) ^ (lr & 7)) * 8;
      short8 a[IF], b[4];
#pragma unroll
      for (int i = 0; i < IF; ++i)
        a[i] = *(const short8*)(As + (wm * (MT / 2) + i * 16 + lr) * 64 + sw);
#pragma unroll
      for (int j = 0; j < 4; ++j)
        b[j] = *(const short8*)(Bs + (wn * 64 + j * 16 + lr) * 64 + sw);
#pragma unroll
      for (int i = 0; i < IF; ++i)
#pragma unroll
        for (int j = 0; j < 4; ++j)
          acc[i][j] = MFMA16(a[i], b[j], acc[i][j]);
    }
    __syncthreads();
  }
}

// ---------------- GEMM kernel: C = A(MxK) * BT(NxK)^T ----------------
// R4-exact for both EPI paths.  C/D layout: col = lane&15 (n),
// row = quad*4 + reg (m).
// EPI==0: QKV -> q (B,H,T,D) PRE-SCALED by 0.125*log2(e), k (B,H,T,D),
//         v packed short4v into V^T (B,H,D,T).
// EPI==1: proj -> fp32 out + bias (scalar dword stores).
template <int EPI, int MT>
__global__ __launch_bounds__(256)
void gemm_bt(const unsigned short* __restrict__ A,
             const unsigned short* __restrict__ BT,
             const float* __restrict__ bias,
             float* __restrict__ outF,
             unsigned short* __restrict__ q_out,
             unsigned short* __restrict__ k_out,
             unsigned short* __restrict__ vT_out,
             int Ndim, int Kdim) {
  constexpr int IF = MT / 32;
  __shared__ __align__(16) unsigned short As[MT * 64];
  __shared__ __align__(16) unsigned short Bs[128 * 64];
  const int tid = threadIdx.x;
  const int wave = tid >> 6, lane = tid & 63;
  const int quad = lane >> 4, lr = lane & 15;
  const int wm = wave >> 1, wn = wave & 1;
  const int m0 = blockIdx.y * MT, n0 = blockIdx.x * 128;

  const int r_l = tid >> 3;
  const int cg = (tid & 7) ^ (r_l & 7);
  const unsigned short* gA = A + (size_t)(m0 + r_l) * Kdim + cg * 8;
  const unsigned short* gB = BT + (size_t)(n0 + r_l) * Kdim + cg * 8;

  f32x4 acc[IF][4] = {};
  gemm_core<MT>(gA, gB, As, Bs, Kdim, wave, quad, lr, wm, wn, acc);

  const int row_t = wm * (MT / 2) + quad * 4;
  const int col_t = wn * 64 + lr;
  if constexpr (EPI == 0) {
    const int sec = n0 >> 10;                 // block-uniform: 0=q 1=k 2=v
    const float scl = (sec == 0) ? 0.18033688f : 1.0f;  // 0.125*log2(e) into Q
#pragma unroll
    for (int j = 0; j < 4; ++j) {
      const int n = n0 + col_t + j * 16;
      const float bi = bias[n];
      const int nn = n & 1023, h = nn >> 6, d = nn & 63;
#pragma unroll
      for (int i = 0; i < IF; ++i) {
        const int m_base = m0 + row_t + i * 16;   // 4 consecutive m for r=0..3
        const int bb = m_base >> 11, t0 = m_base & 2047;
        const int bh = bb * 16 + h;
        if (sec == 2) {
          short4v pk = pack_rne4(acc[i][j][0] + bi, acc[i][j][1] + bi,
                                 acc[i][j][2] + bi, acc[i][j][3] + bi);
          *(short4v*)(vT_out + ((size_t)bh * 64 + d) * 2048 + t0) = pk;
        } else {
          unsigned short* dst = (sec == 0 ? q_out : k_out) + (size_t)bh * 131072 + t0 * 64 + d;
#pragma unroll
          for (int r = 0; r < 4; ++r)
            dst[r * 64] = f2bf((acc[i][j][r] + bi) * scl);
        }
      }
    }
  } else {
#pragma unroll
    for (int i = 0; i < IF; ++i)
#pragma unroll
      for (int r = 0; r < 4; ++r) {
        const int m = m0 + row_t + i * 16 + r;
#pragma unroll
        for (int j = 0; j < 4; ++j) {
          const int n = n0 + col_t + j * 16;
          outF[(size_t)m * Ndim + n] = acc[i][j][r] + bias[n];
        }
      }
  }
}

// ---------------- flash-style causal attention, 64-row q-tiles, split-K ------
// m=0 softmax; Q PRE-SCALED by 0.125*log2(e) so P = exp2(S).
// Transposed-S trick: S^T = K*Q^T; its C-layout IS the K=16 A-operand layout.
// Block = 4 waves x 16 q-rows = 64 q-rows.  DOUBLE-buffered K/V (32 KB),
// 1-tile-ahead: {vmcnt(0); barrier; stage(kt+1); compute}.
// R25 split-K: nch(qt) = ceil((qt+1)/8) = (qt>>3)+1; chunks <= 8 tiles.
// Grid (32 bh, 80), heavy chunks dispatched first:
//   d in [ 0,32): qt = 24+(d&7), ci = d>>3, nch=4
//   d in [32,56): qt = 16+(u&7), ci = u>>3, nch=3   (u = d-32)
//   d in [56,72): qt =  8+(u&7), ci = u>>3, nch=2   (u = d-56)
//   d in [72,80): qt = d-72,     ci = 0,    nch=1 (unsplit, direct y)
// chunk ci covers [ci*nt/nch, (ci+1)*nt/nch), nt = qt+1; only the final
// chunk contains the diagonal (kt==qt) so masking is unchanged.
// Split blocks write fp32 partials (o,l exactly additive — m=0 softmax).
// q,k: (B,H,T,D); v: (B,H,D,T); y: (B,T,C).
__global__ __launch_bounds__(256, 4)
void attn(const unsigned short* __restrict__ qbuf,
          const unsigned short* __restrict__ kbuf,
          const unsigned short* __restrict__ vT,
          unsigned short* __restrict__ yb,
          float* __restrict__ o_part,
          float* __restrict__ l_part) {
  __shared__ __align__(16) unsigned short Ks[2][4096];
  __shared__ __align__(16) unsigned short Vs[2][4096];
  const int tid = threadIdx.x, wave = tid >> 6, lane = tid & 63;
  const int quad = lane >> 4, lr = lane & 15;
  const int bh = blockIdx.x;                  // heads fastest: bh%8 pins XCD
  const int d = (int)blockIdx.y;
  int qt, ci, nch;
  if (d < 32)      { qt = 24 + (d & 7); ci = d >> 3; nch = 4; }
  else if (d < 56) { int u = d - 32; qt = 16 + (u & 7); ci = u >> 3; nch = 3; }
  else if (d < 72) { int u = d - 56; qt = 8 + (u & 7); ci = u >> 3; nch = 2; }
  else             { qt = d - 72; ci = 0; nch = 1; }
  const int nt = qt + 1;
  const int kstart = (ci * nt) / nch;
  const int kend = ((ci + 1) * nt) / nch;
  const int qrow0 = qt * 64;                  // tile base (head-local)

  const unsigned short* qp0 = qbuf + (size_t)bh * 131072;
  const unsigned short* kp0 = kbuf + (size_t)bh * 131072;
  const unsigned short* vp0 = vT   + (size_t)bh * 131072;

  // Q fragments (B-operand of S^T: n = q = lane&15, k = d = quad*8+j)
  short8 aq[2];
  {
    const unsigned short* qp =
        qp0 + (size_t)(qrow0 + wave * 16 + lr) * 64 + quad * 8;
    aq[0] = *(const short8*)qp;
    aq[1] = *(const short8*)(qp + 32);
  }

  short4v ones4;
#pragma unroll
  for (int i = 0; i < 4; ++i) ones4[i] = (short)0x3F80;  // bf16 1.0

  // DMA staging: thread t -> (row=t>>3 in 0..31 (+32), cg=(t&7)^(row&7))
  const int sr = tid >> 3;
  const int scg = (tid & 7) ^ (sr & 7);
  // K fragment bases (A-operand: m = key = lr (+jt*16), k = d = (quad+4h)*8), swizzled
  int kbase[2];
#pragma unroll
  for (int h = 0; h < 2; ++h)
    kbase[h] = lr * 64 + (((quad + 4 * h) ^ (lr & 7)) << 3);
  // V b64 bases per key-block kb: element (row = d = lr (+jd*16), col = kb*16+quad*4)
  int vbase[4];
#pragma unroll
  for (int kb = 0; kb < 4; ++kb)
    vbase[kb] = lr * 64 + (((2 * kb + (quad >> 1)) ^ (lr & 7)) << 3) + (quad & 1) * 4;

  f32x4 o[4] = {};
  f32x4 lacc = {};

  auto stage = [&](int buf, int kt) {
    const unsigned short* kg = kp0 + (size_t)(kt * 64 + sr) * 64 + scg * 8;
    const unsigned short* vg = vp0 + (size_t)sr * 2048 + kt * 64 + scg * 8;
    gl2lds16(kg,             &Ks[buf][wave * 512]);
    gl2lds16(kg + 32 * 64,   &Ks[buf][2048 + wave * 512]);
    gl2lds16(vg,             &Vs[buf][wave * 512]);
    gl2lds16(vg + 32 * 2048, &Vs[buf][2048 + wave * 512]);
  };

  stage(0, kstart);
  int cur = 0;
  for (int kt = kstart; kt < kend; ++kt) {
    // stage(kt) is the only DMA in flight here: vmcnt(0) waits it; barrier
    // publishes tile kt AND proves all waves finished reading tile kt-1
    // (its buffer is about to be reused by stage(kt+1)).
    __builtin_amdgcn_s_waitcnt(0x0F70);       // vmcnt(0)
    __builtin_amdgcn_s_barrier();
    if (kt + 1 < kend) stage(cur ^ 1, kt + 1);  // flies under compute(kt)
    const unsigned short* Kb = Ks[cur];
    const unsigned short* Vb = Vs[cur];
    short8 bk[4][2];
#pragma unroll
    for (int jt = 0; jt < 4; ++jt) {
      bk[jt][0] = *(const short8*)(Kb + jt * 1024 + kbase[0]);
      bk[jt][1] = *(const short8*)(Kb + jt * 1024 + kbase[1]);
    }
    // S^T, exp2 (+causal mask on the diagonal tile), pack; lsum.
    f32x4 s[4] = {};
    __builtin_amdgcn_s_setprio(1);
#pragma unroll
    for (int jt = 0; jt < 4; ++jt) {
      s[jt] = MFMA16(bk[jt][0], aq[0], s[jt]);
      s[jt] = MFMA16(bk[jt][1], aq[1], s[jt]);
    }
    __builtin_amdgcn_s_setprio(0);
    short4v pa[4];
    if (kt == qt) {               // diagonal: key-local > wave*16+lr masked
      const int qloc = wave * 16 + lr;
#pragma unroll
      for (int jt = 0; jt < 4; ++jt) {
        float p[4];
#pragma unroll
        for (int r = 0; r < 4; ++r) {
          p[r] = __builtin_amdgcn_exp2f(s[jt][r]);
          if (jt * 16 + quad * 4 + r > qloc) p[r] = 0.f;
        }
        pa[jt] = pack_bf16x4(p[0], p[1], p[2], p[3]);
      }
    } else {
#pragma unroll
      for (int jt = 0; jt < 4; ++jt) {
        float p[4];
#pragma unroll
        for (int r = 0; r < 4; ++r) p[r] = __builtin_amdgcn_exp2f(s[jt][r]);
        pa[jt] = pack_bf16x4(p[0], p[1], p[2], p[3]);
      }
    }
    __builtin_amdgcn_s_setprio(1);
#pragma unroll
    for (int kb = 0; kb < 4; ++kb)
      lacc = MFMA16K16(ones4, pa[kb], lacc);
    // O += P * V : V b64 reads.
#pragma unroll
    for (int kb = 0; kb < 4; ++kb)
#pragma unroll
      for (int jd = 0; jd < 4; ++jd) {
        const short4v bv = *(const short4v*)(Vb + jd * 1024 + vbase[kb]);
        o[jd] = MFMA16K16(pa[kb], bv, o[jd]);
      }
    __builtin_amdgcn_s_setprio(0);
    cur ^= 1;
  }

  // Epilogue.  o frag: row (within wave's 16 q) = quad*4+r, col = jd*16+lr.
  // lacc[0] at lane i (i<16) = lsum of wave q-row i.
  if (nch == 1) {
    // unsplit: y = o / l directly
    const int b = bh >> 4, h = bh & 15;
    float inv[4];
#pragma unroll
    for (int r = 0; r < 4; ++r)
      inv[r] = __builtin_amdgcn_rcpf(__shfl(lacc[0], quad * 4 + r));
#pragma unroll
    for (int jd = 0; jd < 4; ++jd)
#pragma unroll
      for (int r = 0; r < 4; ++r) {
        const int t = qrow0 + wave * 16 + quad * 4 + r;
        yb[((size_t)b * 2048 + t) * 1024 + h * 64 + jd * 16 + lr] =
            f2bf(o[jd][r] * inv[r]);
      }
  } else {
    // split: fp32 partials.  o_part[(slot*64 + row)*64 + d], l_part[slot*64+row]
    const int slot = (bh * 32 + qt) * 4 + ci;
    float* op = o_part + ((size_t)slot * 64 + wave * 16) * 64;
#pragma unroll
    for (int jd = 0; jd < 4; ++jd)
#pragma unroll
      for (int r = 0; r < 4; ++r)
        op[(quad * 4 + r) * 64 + jd * 16 + lr] = o[jd][r];
    if (lane < 16) l_part[slot * 64 + wave * 16 + lane] = lacc[0];
  }
}

// ---------------- combine: y = (sum o)/(sum l) for split (bh,qt) ----------------
// grid (32 bh, 24); qt = 8+by, nch = (qt>>3)+1 in {2,3,4}.
// 256 threads: row = tid>>2 (0..63), 16 d each.
__global__ __launch_bounds__(256)
void combine(const float* __restrict__ o_part, const float* __restrict__ l_part,
             unsigned short* __restrict__ yb) {
  const int bh = blockIdx.x, qt = 8 + (int)blockIdx.y;
  const int nch = (qt >> 3) + 1;
  const int tid = threadIdx.x;
  const int row = tid >> 2, dd = (tid & 3) * 16;
  const int slot0 = (bh * 32 + qt) * 4;
  float l = 0.f;
  for (int ci = 0; ci < nch; ++ci) l += l_part[(slot0 + ci) * 64 + row];
  const float inv = __builtin_amdgcn_rcpf(l);
  const int b = bh >> 4, h = bh & 15;
  unsigned short* yp = yb + ((size_t)b * 2048 + qt * 64 + row) * 1024 + h * 64 + dd;
#pragma unroll
  for (int j = 0; j < 16; j += 4) {
    float sx = 0.f, sy = 0.f, sz = 0.f, sw = 0.f;
    for (int ci = 0; ci < nch; ++ci) {
      const float4 a4 = *(const float4*)(o_part + ((size_t)(slot0 + ci) * 64 + row) * 64 + dd + j);
      sx += a4.x; sy += a4.y; sz += a4.z; sw += a4.w;
    }
    short4v pk = pack_rne4(sx * inv, sy * inv, sz * inv, sw * inv);
    *(short4v*)(yp + j) = pk;
  }
}

extern "C" void kernel_launch(void* const* d_in, const int* in_sizes, int n_in,
                              void* d_out, int out_size, void* d_ws, size_t ws_size,
                              hipStream_t stream) {
  const float* x     = (const float*)d_in[0];   // (2,2048,1024)
  const float* Wqkv  = (const float*)d_in[1];   // (1024,3072)
  const float* bqkv  = (const float*)d_in[2];   // (3072,)
  const float* Wproj = (const float*)d_in[3];   // (1024,1024)
  const float* bproj = (const float*)d_in[4];   // (1024,)
  float* out = (float*)d_out;                   // (2,2048,1024) fp32

  char* ws = (char*)d_ws;
  unsigned short* xb     = (unsigned short*)(ws);              //  8.0 MB: x bf16 (4096x1024)
  unsigned short* wqkvT  = (unsigned short*)(ws + 8388608);    //  6.0 MB: Wqkv^T bf16 (3072x1024)
  unsigned short* wprojT = (unsigned short*)(ws + 14680064);   //  2.0 MB: Wproj^T bf16 (1024x1024)
  unsigned short* qbuf   = (unsigned short*)(ws + 16777216);   //  8.0 MB: Q (B,H,T,D), pre-scaled
  unsigned short* kbuf   = (unsigned short*)(ws + 25165824);   //  8.0 MB: K (B,H,T,D)
  unsigned short* vTbuf  = (unsigned short*)(ws + 33554432);   //  8.0 MB: V^T (B,H,D,T)
  unsigned short* ybuf   = (unsigned short*)(ws + 41943040);   //  8.0 MB: y (B,T,C) bf16
  float* o_part          = (float*)(ws + 50331648);            // 64.0 MB: split o partials (4096 slots x 64 x 64)
  float* l_part          = (float*)(ws + 117440512);           //  1.0 MB: split l partials

  prep<<<5120, 256, 0, stream>>>(x, xb, Wqkv, wqkvT, Wproj, wprojT);
  gemm_bt<0, 128><<<dim3(24, 32), 256, 0, stream>>>(xb, wqkvT, bqkv, nullptr,
                                                    qbuf, kbuf, vTbuf, 3072, 1024);
  attn<<<dim3(32, 80), 256, 0, stream>>>(qbuf, kbuf, vTbuf, ybuf, o_part, l_part);
  combine<<<dim3(32, 24), 256, 0, stream>>>(o_part, l_part, ybuf);
  gemm_bt<1, 64><<<dim3(8, 64), 256, 0, stream>>>(ybuf, wprojT, bproj, out,
                                                  nullptr, nullptr, nullptr, 1024, 1024);
}

// Round 15
// 175.400 us; speedup vs baseline: 1.0870x; 1.0870x over previous
//
#include <hip/hip_runtime.h>

// CausalSelfAttention on MI355X (gfx950), bf16 MFMA pipeline.
// B=2 T=2048 C=1024 NH=16 HD=64.  M=B*T=4096.
//
// R26: FINAL — revert to the session-best configuration (R13/R24 source,
// byte-exact; measured 177.26 and 176.86 us).  R25's uniform <=8-tile split
// was falsified per its pre-committed test: attn 41.5->42.5 us (per-chunk
// fixed overhead — Q load, prologue drain, 20 KB partial write — now paid
// 80x/bh vs 48x; WRITE 20.7->39.5 MB; combine doubled).  The makespan is
// aggregate-bound (~2.5 us/tile x ~16.5 tiles/block-slot) + fixed overhead,
// not chain-bound.  Session ledger (14 experiments):
//   QKV  = R4 core, ~48 us: 3 pipelining variants (triple-buf, 2-phase dbuf,
//          counted-vmcnt) all regressed via LDS-residency loss; epilogue
//          swaps all regressed via K-loop codegen (VGPR/occupancy).
//   attn = 64-row split-K (chunks <=16, m=0 softmax additive partials),
//          ~41.5 us: 128-row two-group falsified (49 us); <=8-split
//          falsified (42.5); occupancy/buffering changes neutral.
//   proj ~16 us, prep ~10, combine ~4.  ~60 us fixed harness overhead
//   (256 MiB poison fills at 42-45 us each) dominates the remainder.

typedef __attribute__((ext_vector_type(8))) short short8;   // 8 x bf16 (4 VGPR)
typedef __attribute__((ext_vector_type(4))) short short4v;  // 4 x bf16 (2 VGPR, align 8)
typedef __attribute__((ext_vector_type(4))) float f32x4;    // MFMA 16x16 acc
typedef __attribute__((ext_vector_type(2))) unsigned int u32x2;

#define MFMA16(a, b, c) __builtin_amdgcn_mfma_f32_16x16x32_bf16((a), (b), (c), 0, 0, 0)
#define MFMA16K16(a, b, c) __builtin_amdgcn_mfma_f32_16x16x16bf16_1k((a), (b), (c), 0, 0, 0)

__device__ __forceinline__ unsigned short f2bf(float f) {
  unsigned u = __builtin_bit_cast(unsigned, f);
  u += 0x7fffu + ((u >> 16) & 1u);   // RNE
  return (unsigned short)(u >> 16);
}

__device__ __forceinline__ unsigned short f2bf_fast(float f) {
  // round-half-up: cheaper (2 VALU); |err| <= 2^-9 rel, fine for P/y
  return (unsigned short)((__builtin_bit_cast(unsigned, f) + 0x8000u) >> 16);
}

#if __has_builtin(__builtin_amdgcn_cvt_pk_bf16_f32)
typedef __attribute__((ext_vector_type(2))) __bf16 bf16x2;
__device__ __forceinline__ short4v pack_bf16x4(float a, float b, float c, float d) {
  bf16x2 lo = __builtin_amdgcn_cvt_pk_bf16_f32(a, b);
  bf16x2 hi = __builtin_amdgcn_cvt_pk_bf16_f32(c, d);
  u32x2 t;
  t[0] = __builtin_bit_cast(unsigned, lo);
  t[1] = __builtin_bit_cast(unsigned, hi);
  return __builtin_bit_cast(short4v, t);
}
#else
__device__ __forceinline__ short4v pack_bf16x4(float a, float b, float c, float d) {
  short4v r;
  r[0] = (short)f2bf_fast(a); r[1] = (short)f2bf_fast(b);
  r[2] = (short)f2bf_fast(c); r[3] = (short)f2bf_fast(d);
  return r;
}
#endif

__device__ __forceinline__ short4v pack_rne4(float a, float b, float c, float d) {
  short4v r;
  r[0] = (short)f2bf(a); r[1] = (short)f2bf(b);
  r[2] = (short)f2bf(c); r[3] = (short)f2bf(d);
  return r;
}

__device__ __forceinline__ void gl2lds16(const void* g, void* l) {
  // async global->LDS, 16B/lane; LDS dest = wave-uniform base + lane*16
  __builtin_amdgcn_global_load_lds(
      (__attribute__((address_space(1))) void*)g,
      (__attribute__((address_space(3))) void*)l,
      16, 0, 0);
}

// ---------------- merged prep: x->bf16 + both weight transposes ----------------
// blocks [0,4096): conv x (4096x1024 fp32 -> bf16)
// blocks [4096,4864): Wqkv (1024x3072) -> Wqkv^T bf16 (3072x1024), 48x16 tiles
// blocks [4864,5120): Wproj (1024x1024) -> Wproj^T bf16, 16x16 tiles
// Branch is block-uniform, so the __syncthreads in the transpose path is safe.
__global__ __launch_bounds__(256)
void prep(const float* __restrict__ x, unsigned short* __restrict__ xb,
          const float* __restrict__ Wqkv, unsigned short* __restrict__ wqkvT,
          const float* __restrict__ Wproj, unsigned short* __restrict__ wprojT) {
  __shared__ float tile[64][65];
  const int bx = blockIdx.x, tid = threadIdx.x;
  if (bx < 4096) {
    const int i = (bx * 256 + tid) * 4;
    float4 f = *(const float4*)(x + i);
    unsigned long long r = (unsigned long long)f2bf(f.x)
        | ((unsigned long long)f2bf(f.y) << 16)
        | ((unsigned long long)f2bf(f.z) << 32)
        | ((unsigned long long)f2bf(f.w) << 48);
    *(unsigned long long*)(xb + i) = r;
    return;
  }
  const float* W;
  unsigned short* WT;
  int n0, k0, N;
  if (bx < 4864) {
    const int idx = bx - 4096;            // 48 x 16 tiles, N=3072
    W = Wqkv; WT = wqkvT; N = 3072;
    n0 = (idx % 48) * 64; k0 = (idx / 48) * 64;
  } else {
    const int idx = bx - 4864;            // 16 x 16 tiles, N=1024
    W = Wproj; WT = wprojT; N = 1024;
    n0 = (idx % 16) * 64; k0 = (idx / 16) * 64;
  }
  const int K = 1024;
  const int c = tid & 63, rbase = tid >> 6;  // 4 rows per pass, 16 passes
#pragma unroll
  for (int i = 0; i < 16; ++i) {
    int r = i * 4 + rbase;
    tile[r][c] = W[(size_t)(k0 + r) * N + n0 + c];
  }
  __syncthreads();
#pragma unroll
  for (int i = 0; i < 16; ++i) {
    int r = i * 4 + rbase;
    WT[(size_t)(n0 + r) * K + k0 + c] = f2bf(tile[c][r]);
  }
}

// ---------------- GEMM core: staging + MFMA loop ----------------
// R1 structure: single-buffered 32 KB LDS -> ~3 blocks/CU; stage -> sync ->
// compute -> sync; cross-block TLP hides the drain.
template <int MT>
__device__ __forceinline__ void gemm_core(
    const unsigned short* __restrict__ gA,
    const unsigned short* __restrict__ gB,
    unsigned short* As, unsigned short* Bs,
    int Kdim, int wave, int quad, int lr, int wm, int wn,
    f32x4 (&acc)[MT / 32][4]) {
  constexpr int IF = MT / 32;
  constexpr int RA = MT / 32;
  const size_t rstep = (size_t)32 * Kdim;
  for (int k0 = 0; k0 < Kdim; k0 += 64) {
#pragma unroll
    for (int rd = 0; rd < RA; ++rd)
      gl2lds16(gA + k0 + rd * rstep, As + rd * 2048 + wave * 512);
#pragma unroll
    for (int rd = 0; rd < 4; ++rd)
      gl2lds16(gB + k0 + rd * rstep, Bs + rd * 2048 + wave * 512);
    __syncthreads();
#pragma unroll
    for (int s = 0; s < 2; ++s) {
      const int sw = ((s * 4 + quad) ^ (lr & 7)) * 8;
      short8 a[IF], b[4];
#pragma unroll
      for (int i = 0; i < IF; ++i)
        a[i] = *(const short8*)(As + (wm * (MT / 2) + i * 16 + lr) * 64 + sw);
#pragma unroll
      for (int j = 0; j < 4; ++j)
        b[j] = *(const short8*)(Bs + (wn * 64 + j * 16 + lr) * 64 + sw);
#pragma unroll
      for (int i = 0; i < IF; ++i)
#pragma unroll
        for (int j = 0; j < 4; ++j)
          acc[i][j] = MFMA16(a[i], b[j], acc[i][j]);
    }
    __syncthreads();
  }
}

// ---------------- GEMM kernel: C = A(MxK) * BT(NxK)^T ----------------
// R4-exact for both EPI paths.  C/D layout: col = lane&15 (n),
// row = quad*4 + reg (m).
// EPI==0: QKV -> q (B,H,T,D) PRE-SCALED by 0.125*log2(e), k (B,H,T,D),
//         v packed short4v into V^T (B,H,D,T).
// EPI==1: proj -> fp32 out + bias (scalar dword stores).
template <int EPI, int MT>
__global__ __launch_bounds__(256)
void gemm_bt(const unsigned short* __restrict__ A,
             const unsigned short* __restrict__ BT,
             const float* __restrict__ bias,
             float* __restrict__ outF,
             unsigned short* __restrict__ q_out,
             unsigned short* __restrict__ k_out,
             unsigned short* __restrict__ vT_out,
             int Ndim, int Kdim) {
  constexpr int IF = MT / 32;
  __shared__ __align__(16) unsigned short As[MT * 64];
  __shared__ __align__(16) unsigned short Bs[128 * 64];
  const int tid = threadIdx.x;
  const int wave = tid >> 6, lane = tid & 63;
  const int quad = lane >> 4, lr = lane & 15;
  const int wm = wave >> 1, wn = wave & 1;
  const int m0 = blockIdx.y * MT, n0 = blockIdx.x * 128;

  const int r_l = tid >> 3;
  const int cg = (tid & 7) ^ (r_l & 7);
  const unsigned short* gA = A + (size_t)(m0 + r_l) * Kdim + cg * 8;
  const unsigned short* gB = BT + (size_t)(n0 + r_l) * Kdim + cg * 8;

  f32x4 acc[IF][4] = {};
  gemm_core<MT>(gA, gB, As, Bs, Kdim, wave, quad, lr, wm, wn, acc);

  const int row_t = wm * (MT / 2) + quad * 4;
  const int col_t = wn * 64 + lr;
  if constexpr (EPI == 0) {
    const int sec = n0 >> 10;                 // block-uniform: 0=q 1=k 2=v
    const float scl = (sec == 0) ? 0.18033688f : 1.0f;  // 0.125*log2(e) into Q
#pragma unroll
    for (int j = 0; j < 4; ++j) {
      const int n = n0 + col_t + j * 16;
      const float bi = bias[n];
      const int nn = n & 1023, h = nn >> 6, d = nn & 63;
#pragma unroll
      for (int i = 0; i < IF; ++i) {
        const int m_base = m0 + row_t + i * 16;   // 4 consecutive m for r=0..3
        const int bb = m_base >> 11, t0 = m_base & 2047;
        const int bh = bb * 16 + h;
        if (sec == 2) {
          short4v pk = pack_rne4(acc[i][j][0] + bi, acc[i][j][1] + bi,
                                 acc[i][j][2] + bi, acc[i][j][3] + bi);
          *(short4v*)(vT_out + ((size_t)bh * 64 + d) * 2048 + t0) = pk;
        } else {
          unsigned short* dst = (sec == 0 ? q_out : k_out) + (size_t)bh * 131072 + t0 * 64 + d;
#pragma unroll
          for (int r = 0; r < 4; ++r)
            dst[r * 64] = f2bf((acc[i][j][r] + bi) * scl);
        }
      }
    }
  } else {
#pragma unroll
    for (int i = 0; i < IF; ++i)
#pragma unroll
      for (int r = 0; r < 4; ++r) {
        const int m = m0 + row_t + i * 16 + r;
#pragma unroll
        for (int j = 0; j < 4; ++j) {
          const int n = n0 + col_t + j * 16;
          outF[(size_t)m * Ndim + n] = acc[i][j][r] + bias[n];
        }
      }
  }
}

// ---------------- flash-style causal attention, 64-row q-tiles, split-K ------
// m=0 softmax; Q PRE-SCALED by 0.125*log2(e) so P = exp2(S).
// Transposed-S trick: S^T = K*Q^T; its C-layout IS the K=16 A-operand layout.
// Block = 4 waves x 16 q-rows = 64 q-rows.  DOUBLE-buffered K/V (32 KB),
// 1-tile-ahead: {vmcnt(0); barrier; stage(kt+1); compute}.
// Split-K: grid (32 bh, 48); jj = 47-by (heavy-first):
//   jj in [32,48): qt=jj-16, chunk B = [(qt+1)/2, qt+1)  (9-16 tiles, diag)
//   jj in [16,32): qt=jj,    chunk A = [0, (qt+1)/2)     (8-16 tiles)
//   jj in [0,16):  qt=jj,    unsplit  [0, qt+1)          (1-16 tiles)
// Split blocks write fp32 partials (o,l additive — m=0 softmax); unsplit
// write y directly.  1536 blocks vs 5/CU LDS capacity -> refill queue.
// q,k: (B,H,T,D); v: (B,H,D,T); y: (B,T,C).
__global__ __launch_bounds__(256, 4)
void attn(const unsigned short* __restrict__ qbuf,
          const unsigned short* __restrict__ kbuf,
          const unsigned short* __restrict__ vT,
          unsigned short* __restrict__ yb,
          float* __restrict__ o_part,
          float* __restrict__ l_part) {
  __shared__ __align__(16) unsigned short Ks[2][4096];
  __shared__ __align__(16) unsigned short Vs[2][4096];
  const int tid = threadIdx.x, wave = tid >> 6, lane = tid & 63;
  const int quad = lane >> 4, lr = lane & 15;
  const int bh = blockIdx.x;                  // heads fastest: bh%8 pins XCD
  const int jj = 47 - (int)blockIdx.y;        // heavy-first
  int qt, kstart, kend, chunk;
  if (jj >= 32)      { qt = jj - 16; chunk = 1; kstart = (qt + 1) >> 1; kend = qt + 1; }
  else if (jj >= 16) { qt = jj;      chunk = 0; kstart = 0; kend = (qt + 1) >> 1; }
  else               { qt = jj;      chunk = -1; kstart = 0; kend = qt + 1; }
  const int qrow0 = qt * 64;                  // tile base (head-local)

  const unsigned short* qp0 = qbuf + (size_t)bh * 131072;
  const unsigned short* kp0 = kbuf + (size_t)bh * 131072;
  const unsigned short* vp0 = vT   + (size_t)bh * 131072;

  // Q fragments (B-operand of S^T: n = q = lane&15, k = d = quad*8+j)
  short8 aq[2];
  {
    const unsigned short* qp =
        qp0 + (size_t)(qrow0 + wave * 16 + lr) * 64 + quad * 8;
    aq[0] = *(const short8*)qp;
    aq[1] = *(const short8*)(qp + 32);
  }

  short4v ones4;
#pragma unroll
  for (int i = 0; i < 4; ++i) ones4[i] = (short)0x3F80;  // bf16 1.0

  // DMA staging: thread t -> (row=t>>3 in 0..31 (+32), cg=(t&7)^(row&7))
  const int sr = tid >> 3;
  const int scg = (tid & 7) ^ (sr & 7);
  // K fragment bases (A-operand: m = key = lr (+jt*16), k = d = (quad+4h)*8), swizzled
  int kbase[2];
#pragma unroll
  for (int h = 0; h < 2; ++h)
    kbase[h] = lr * 64 + (((quad + 4 * h) ^ (lr & 7)) << 3);
  // V b64 bases per key-block kb: element (row = d = lr (+jd*16), col = kb*16+quad*4)
  int vbase[4];
#pragma unroll
  for (int kb = 0; kb < 4; ++kb)
    vbase[kb] = lr * 64 + (((2 * kb + (quad >> 1)) ^ (lr & 7)) << 3) + (quad & 1) * 4;

  f32x4 o[4] = {};
  f32x4 lacc = {};

  auto stage = [&](int buf, int kt) {
    const unsigned short* kg = kp0 + (size_t)(kt * 64 + sr) * 64 + scg * 8;
    const unsigned short* vg = vp0 + (size_t)sr * 2048 + kt * 64 + scg * 8;
    gl2lds16(kg,             &Ks[buf][wave * 512]);
    gl2lds16(kg + 32 * 64,   &Ks[buf][2048 + wave * 512]);
    gl2lds16(vg,             &Vs[buf][wave * 512]);
    gl2lds16(vg + 32 * 2048, &Vs[buf][2048 + wave * 512]);
  };

  stage(0, kstart);
  int cur = 0;
  for (int kt = kstart; kt < kend; ++kt) {
    // stage(kt) is the only DMA in flight here: vmcnt(0) waits it; barrier
    // publishes tile kt AND proves all waves finished reading tile kt-1
    // (its buffer is about to be reused by stage(kt+1)).
    __builtin_amdgcn_s_waitcnt(0x0F70);       // vmcnt(0)
    __builtin_amdgcn_s_barrier();
    if (kt + 1 < kend) stage(cur ^ 1, kt + 1);  // flies under compute(kt)
    const unsigned short* Kb = Ks[cur];
    const unsigned short* Vb = Vs[cur];
    short8 bk[4][2];
#pragma unroll
    for (int jt = 0; jt < 4; ++jt) {
      bk[jt][0] = *(const short8*)(Kb + jt * 1024 + kbase[0]);
      bk[jt][1] = *(const short8*)(Kb + jt * 1024 + kbase[1]);
    }
    // S^T, exp2 (+causal mask on the diagonal tile), pack; lsum.
    f32x4 s[4] = {};
    __builtin_amdgcn_s_setprio(1);
#pragma unroll
    for (int jt = 0; jt < 4; ++jt) {
      s[jt] = MFMA16(bk[jt][0], aq[0], s[jt]);
      s[jt] = MFMA16(bk[jt][1], aq[1], s[jt]);
    }
    __builtin_amdgcn_s_setprio(0);
    short4v pa[4];
    if (kt == qt) {               // diagonal: key-local > wave*16+lr masked
      const int qloc = wave * 16 + lr;
#pragma unroll
      for (int jt = 0; jt < 4; ++jt) {
        float p[4];
#pragma unroll
        for (int r = 0; r < 4; ++r) {
          p[r] = __builtin_amdgcn_exp2f(s[jt][r]);
          if (jt * 16 + quad * 4 + r > qloc) p[r] = 0.f;
        }
        pa[jt] = pack_bf16x4(p[0], p[1], p[2], p[3]);
      }
    } else {
#pragma unroll
      for (int jt = 0; jt < 4; ++jt) {
        float p[4];
#pragma unroll
        for (int r = 0; r < 4; ++r) p[r] = __builtin_amdgcn_exp2f(s[jt][r]);
        pa[jt] = pack_bf16x4(p[0], p[1], p[2], p[3]);
      }
    }
    __builtin_amdgcn_s_setprio(1);
#pragma unroll
    for (int kb = 0; kb < 4; ++kb)
      lacc = MFMA16K16(ones4, pa[kb], lacc);
    // O += P * V : V b64 reads.
#pragma unroll
    for (int kb = 0; kb < 4; ++kb)
#pragma unroll
      for (int jd = 0; jd < 4; ++jd) {
        const short4v bv = *(const short4v*)(Vb + jd * 1024 + vbase[kb]);
        o[jd] = MFMA16K16(pa[kb], bv, o[jd]);
      }
    __builtin_amdgcn_s_setprio(0);
    cur ^= 1;
  }

  // Epilogue.  o frag: row (within wave's 16 q) = quad*4+r, col = jd*16+lr.
  // lacc[0] at lane i (i<16) = lsum of wave q-row i.
  if (chunk < 0) {
    // unsplit: y = o / l directly
    const int b = bh >> 4, h = bh & 15;
    float inv[4];
#pragma unroll
    for (int r = 0; r < 4; ++r)
      inv[r] = __builtin_amdgcn_rcpf(__shfl(lacc[0], quad * 4 + r));
#pragma unroll
    for (int jd = 0; jd < 4; ++jd)
#pragma unroll
      for (int r = 0; r < 4; ++r) {
        const int t = qrow0 + wave * 16 + quad * 4 + r;
        yb[((size_t)b * 2048 + t) * 1024 + h * 64 + jd * 16 + lr] =
            f2bf(o[jd][r] * inv[r]);
      }
  } else {
    // split: fp32 partials.  o_part[(slot*64 + row)*64 + d], l_part[slot*64+row]
    const int slot = (bh * 16 + (qt - 16)) * 2 + chunk;
    float* op = o_part + ((size_t)slot * 64 + wave * 16) * 64;
#pragma unroll
    for (int jd = 0; jd < 4; ++jd)
#pragma unroll
      for (int r = 0; r < 4; ++r)
        op[(quad * 4 + r) * 64 + jd * 16 + lr] = o[jd][r];
    if (lane < 16) l_part[slot * 64 + wave * 16 + lane] = lacc[0];
  }
}

// ---------------- combine: y = (oA+oB)/(lA+lB) for split (bh,qt) ----------------
// grid (32 bh, 16 qtl); qt = 16+qtl.  256 threads: row = tid>>2, 16 d each.
__global__ __launch_bounds__(256)
void combine(const float* __restrict__ o_part, const float* __restrict__ l_part,
             unsigned short* __restrict__ yb) {
  const int bh = blockIdx.x, qtl = blockIdx.y;
  const int tid = threadIdx.x;
  const int row = tid >> 2, dd = (tid & 3) * 16;
  const int qt = 16 + qtl;
  const int slotA = (bh * 16 + qtl) * 2, slotB = slotA + 1;
  const float l = l_part[slotA * 64 + row] + l_part[slotB * 64 + row];
  const float inv = __builtin_amdgcn_rcpf(l);
  const float* oa = o_part + ((size_t)slotA * 64 + row) * 64 + dd;
  const float* ob = o_part + ((size_t)slotB * 64 + row) * 64 + dd;
  const int b = bh >> 4, h = bh & 15;
  unsigned short* yp = yb + ((size_t)b * 2048 + qt * 64 + row) * 1024 + h * 64 + dd;
#pragma unroll
  for (int j = 0; j < 16; j += 4) {
    const float4 a4 = *(const float4*)(oa + j);
    const float4 b4 = *(const float4*)(ob + j);
    short4v pk = pack_rne4((a4.x + b4.x) * inv, (a4.y + b4.y) * inv,
                           (a4.z + b4.z) * inv, (a4.w + b4.w) * inv);
    *(short4v*)(yp + j) = pk;
  }
}

extern "C" void kernel_launch(void* const* d_in, const int* in_sizes, int n_in,
                              void* d_out, int out_size, void* d_ws, size_t ws_size,
                              hipStream_t stream) {
  const float* x     = (const float*)d_in[0];   // (2,2048,1024)
  const float* Wqkv  = (const float*)d_in[1];   // (1024,3072)
  const float* bqkv  = (const float*)d_in[2];   // (3072,)
  const float* Wproj = (const float*)d_in[3];   // (1024,1024)
  const float* bproj = (const float*)d_in[4];   // (1024,)
  float* out = (float*)d_out;                   // (2,2048,1024) fp32

  char* ws = (char*)d_ws;
  unsigned short* xb     = (unsigned short*)(ws);              //  8.0 MB: x bf16 (4096x1024)
  unsigned short* wqkvT  = (unsigned short*)(ws + 8388608);    //  6.0 MB: Wqkv^T bf16 (3072x1024)
  unsigned short* wprojT = (unsigned short*)(ws + 14680064);   //  2.0 MB: Wproj^T bf16 (1024x1024)
  unsigned short* qbuf   = (unsigned short*)(ws + 16777216);   //  8.0 MB: Q (B,H,T,D), pre-scaled
  unsigned short* kbuf   = (unsigned short*)(ws + 25165824);   //  8.0 MB: K (B,H,T,D)
  unsigned short* vTbuf  = (unsigned short*)(ws + 33554432);   //  8.0 MB: V^T (B,H,D,T)
  unsigned short* ybuf   = (unsigned short*)(ws + 41943040);   //  8.0 MB: y (B,T,C) bf16
  float* o_part          = (float*)(ws + 50331648);            // 16.8 MB: split o partials
  float* l_part          = (float*)(ws + 67108864);            //  0.25 MB: split l partials

  prep<<<5120, 256, 0, stream>>>(x, xb, Wqkv, wqkvT, Wproj, wprojT);
  gemm_bt<0, 128><<<dim3(24, 32), 256, 0, stream>>>(xb, wqkvT, bqkv, nullptr,
                                                    qbuf, kbuf, vTbuf, 3072, 1024);
  attn<<<dim3(32, 48), 256, 0, stream>>>(qbuf, kbuf, vTbuf, ybuf, o_part, l_part);
  combine<<<dim3(32, 16), 256, 0, stream>>>(o_part, l_part, ybuf);
  gemm_bt<1, 64><<<dim3(8, 64), 256, 0, stream>>>(ybuf, wprojT, bproj, out,
                                                  nullptr, nullptr, nullptr, 1024, 1024);
}